// Round 4
// baseline (3788.609 us; speedup 1.0000x reference)
//
#include <hip/hip_runtime.h>
#include <cstdint>
#include <cstddef>

#define BATCH 128
#define TLEN 4096
#define KS 64
#define NCHUNK 64  // chunk c covers t in [64c+1, min(64c+64, 4095)]

typedef __attribute__((ext_vector_type(2))) float f32x2;
typedef __attribute__((ext_vector_type(4))) float f32x4;

__device__ __forceinline__ float f3(float a, float b, float c) {
  return fmaxf(fmaxf(a, b), c);  // folds to v_max3_f32
}

// scalar max over m[64]; used by crf_bp. fp32 max is exact (returns an input
// bitwise), so ANY tree shape yields states identical to fwd's packed tree.
__device__ __forceinline__ float tree64(const float* m) {
  float t[22];
#pragma unroll
  for (int i = 0; i < 21; ++i) t[i] = f3(m[3 * i], m[3 * i + 1], m[3 * i + 2]);
  t[21] = m[63];
#pragma unroll
  for (int i = 0; i < 7; ++i) t[i] = f3(t[3 * i], t[3 * i + 1], t[3 * i + 2]);
  t[7] = t[21];
  t[0] = f3(t[0], t[1], t[2]);
  t[1] = f3(t[3], t[4], t[5]);
  t[2] = t[6];
  t[3] = t[7];
  t[0] = f3(t[0], t[1], t[2]);
  return fmaxf(t[0], t[3]);
}

// packed max: component-wise (x = chain A, y = chain B; components never mix)
__device__ __forceinline__ f32x2 vmax2(f32x2 a, f32x2 b) {
  return __builtin_elementwise_max(a, b);
}
__device__ __forceinline__ f32x2 f3p(f32x2 a, f32x2 b, f32x2 c) {
  return vmax2(vmax2(a, b), c);
}
__device__ __forceinline__ f32x2 tree64p(const f32x2* m) {
  f32x2 t[22];
#pragma unroll
  for (int i = 0; i < 21; ++i) t[i] = f3p(m[3 * i], m[3 * i + 1], m[3 * i + 2]);
  t[21] = m[63];
#pragma unroll
  for (int i = 0; i < 7; ++i) t[i] = f3p(t[3 * i], t[3 * i + 1], t[3 * i + 2]);
  t[7] = t[21];
  t[0] = f3p(t[0], t[1], t[2]);
  t[1] = f3p(t[3], t[4], t[5]);
  t[2] = t[6];
  t[3] = t[7];
  t[0] = f3p(t[0], t[1], t[2]);
  return vmax2(t[0], t[3]);
}

// ---------------------------------------------------------------------------
// Forward recurrence: TWO independent batch chains per wave, packed in f32x2
// lanes. One wave per block; LDS broadcast with no barrier (single-wave
// in-order LDS). Chain B's issue hides chain A's LDS latency (and packed ops
// share instructions). No argmax on the critical path; checkpoints every 64
// steps feed the parallel bp-reconstruction kernel.
// ---------------------------------------------------------------------------
__global__ __launch_bounds__(64, 1) void crf_fwd(
    const float* __restrict__ pot, const float* __restrict__ trans,
    float* __restrict__ cp, float* __restrict__ fin) {
  const int bb = blockIdx.x;  // handles batches 2bb, 2bb+1
  const int j = threadIdx.x;
  __shared__ f32x4 smq[KS / 2];  // = f32x2 sm[64], 16B-aligned
  f32x2* sm = (f32x2*)smq;

  // transitions column j, splatted to both halves (enables v_pk_add_f32)
  f32x2 c2[KS];
#pragma unroll
  for (int i = 0; i < KS; ++i) {
    float v = trans[i * KS + j];
    c2[i].x = v;
    c2[i].y = v;
  }

  const float* p0 = pot + (size_t)(2 * bb) * TLEN * KS + j;
  const float* p1 = pot + (size_t)(2 * bb + 1) * TLEN * KS + j;
  float* cp0 = cp + (size_t)(2 * bb) * NCHUNK * KS + j;
  float* cp1 = cp + (size_t)(2 * bb + 1) * NCHUNK * KS + j;

  f32x2 s;
  s.x = p0[0];
  s.y = p1[0];
  cp0[0] = s.x;
  cp1[0] = s.y;
  sm[j] = s;

  // 4-deep emission prefetch ring per chain (HBM latency ~900 cyc ≈ 3 steps)
  f32x2 ef[4];
#pragma unroll
  for (int q = 0; q < 4; ++q) {
    ef[q].x = p0[(size_t)(1 + q) * KS];
    ef[q].y = p1[(size_t)(1 + q) * KS];
  }

#pragma unroll 2
  for (int t = 1; t < TLEN; ++t) {
    f32x2 emit = ef[(t - 1) & 3];
    int tp = t + 4;
    tp = tp > TLEN - 1 ? TLEN - 1 : tp;
    f32x2 nf;
    nf.x = p0[(size_t)tp * KS];
    nf.y = p1[(size_t)tp * KS];
    ef[(t - 1) & 3] = nf;

    // broadcast-read both chains' state vectors (same-address b128 reads)
    f32x2 m2[KS];
#pragma unroll
    for (int q = 0; q < KS / 2; ++q) {
      f32x4 v = smq[q];
      f32x2 a;
      a.x = v.x;
      a.y = v.y;
      f32x2 b;
      b.x = v.z;
      b.y = v.w;
      m2[2 * q] = a + c2[2 * q];
      m2[2 * q + 1] = b + c2[2 * q + 1];
    }
    s = tree64p(m2) + emit;
    sm[j] = s;  // single-wave in-order LDS: next iteration's reads see this
    if ((t & 63) == 0) {
      int ci = t >> 6;
      cp0[(size_t)ci * KS] = s.x;
      cp1[(size_t)ci * KS] = s.y;
    }
  }
  fin[(size_t)(2 * bb) * KS + j] = s.x;
  fin[(size_t)(2 * bb + 1) * KS + j] = s.y;
}

// ---------------------------------------------------------------------------
// Backpointer reconstruction: per (batch, chunk) wave recomputes states from
// the checkpoint (bit-identical: fp32 max is exact, sums identical), derives
// bp[t][j] for all j, and fuses the speculative chunk-map chase via
// ds_bpermute. 8192 waves -> chain latency hidden by TLP.
// ---------------------------------------------------------------------------
__global__ __launch_bounds__(64) void crf_bp(
    const float* __restrict__ pot, const float* __restrict__ trans,
    const float* __restrict__ cp, unsigned char* __restrict__ bp,
    unsigned char* __restrict__ map) {
  const int b = blockIdx.x;
  const int ch = blockIdx.y;
  const int j = threadIdx.x;
  __shared__ float4 sm4[KS / 4];
  float* sm = (float*)sm4;

  float c[KS];
#pragma unroll
  for (int i = 0; i < KS; ++i) c[i] = trans[i * KS + j];

  float s = cp[((size_t)b * NCHUNK + ch) * KS + j];
  const int t0 = ch * 64;
  const int hi = min(t0 + 64, TLEN - 1);
  const float* pb = pot + (size_t)b * TLEN * KS + j;
  unsigned char* bpb = bp + (size_t)b * TLEN * KS + j;

  sm[j] = s;
  int tag = j;  // forward-composed backward map
  float emit = pb[(size_t)(t0 + 1) * KS];
  for (int t = t0 + 1; t <= hi; ++t) {
    float emit_next = pb[(size_t)min(t + 1, TLEN - 1) * KS];

    float m[KS];
#pragma unroll
    for (int q = 0; q < KS / 4; ++q) {
      float4 v = sm4[q];
      m[4 * q + 0] = v.x + c[4 * q + 0];
      m[4 * q + 1] = v.y + c[4 * q + 1];
      m[4 * q + 2] = v.z + c[4 * q + 2];
      m[4 * q + 3] = v.w + c[4 * q + 3];
    }
    float best = tree64(m);

    // first-occurrence argmax: descending exact-equality scan
    int bi = 63;
#pragma unroll
    for (int i = 62; i >= 0; --i) bi = (m[i] == best) ? i : bi;

    bpb[(size_t)t * KS] = (unsigned char)bi;
    s = best + emit;
    sm[j] = s;
    emit = emit_next;

    // g_t[k] = g_{t-1}[bp_t[k]]: lane k pulls lane bi_k's tag
    tag = __builtin_amdgcn_ds_bpermute(bi << 2, tag);
  }
  map[((size_t)b * NCHUNK + ch) * KS + j] = (unsigned char)tag;
}

// ---------------------------------------------------------------------------
// Compose chunk maps per batch (serial over 64 chunks, parallel over batches).
// Also does the final-state argmax (first-occurrence, strict >).
// ---------------------------------------------------------------------------
__global__ void crf_compose(const unsigned char* __restrict__ map,
                            const float* __restrict__ fin,
                            unsigned char* __restrict__ e,
                            int* __restrict__ tags_out) {
  const int b = blockIdx.x * blockDim.x + threadIdx.x;
  if (b >= BATCH) return;
  const float* fb = fin + (size_t)b * KS;
  float best = fb[0];
  int cur = 0;
  for (int i = 1; i < KS; ++i) {
    float v = fb[i];
    if (v > best) { best = v; cur = i; }
  }
  tags_out[(size_t)b * TLEN + (TLEN - 1)] = cur;
  for (int ch = NCHUNK - 1; ch >= 0; --ch) {
    e[(size_t)b * NCHUNK + ch] = (unsigned char)cur;
    cur = map[((size_t)b * NCHUNK + ch) * KS + cur];
  }
}

// ---------------------------------------------------------------------------
// Extract per-chunk paths from known entering tags (parallel over B*NCHUNK).
// ---------------------------------------------------------------------------
__global__ void crf_extract(const unsigned char* __restrict__ bp,
                            const unsigned char* __restrict__ e,
                            int* __restrict__ tags_out) {
  const int idx = blockIdx.x * blockDim.x + threadIdx.x;  // b*NCHUNK + c
  if (idx >= BATCH * NCHUNK) return;
  const int b = idx >> 6;
  const int c = idx & (NCHUNK - 1);
  const int lo = 64 * c + 1;
  const int hi = min(64 * c + 64, TLEN - 1);
  const unsigned char* bpb = bp + (size_t)b * TLEN * KS;
  int* to = tags_out + (size_t)b * TLEN;
  int tag = e[(size_t)b * NCHUNK + c];
  for (int t = hi; t >= lo; --t) {
    tag = bpb[(size_t)t * KS + tag];
    to[t - 1] = tag;
  }
}

// ---------------------------------------------------------------------------
// Sequence lengths = sum(mask) per batch.
// ---------------------------------------------------------------------------
__global__ __launch_bounds__(64) void crf_lens(const int* __restrict__ mask,
                                               int* __restrict__ out) {
  const int b = blockIdx.x;
  const int l = threadIdx.x;
  const int* mb = mask + (size_t)b * TLEN;
  int sum = 0;
  for (int t = l; t < TLEN; t += 64) sum += mb[t];
#pragma unroll
  for (int off = 32; off > 0; off >>= 1) sum += __shfl_down(sum, off, 64);
  if (l == 0) out[b] = sum;
}

extern "C" void kernel_launch(void* const* d_in, const int* in_sizes, int n_in,
                              void* d_out, int out_size, void* d_ws,
                              size_t ws_size, hipStream_t stream) {
  const float* pot = (const float*)d_in[0];    // (128, 4096, 64) fp32
  const float* trans = (const float*)d_in[1];  // (64, 64) fp32
  const int* mask = (const int*)d_in[2];       // (128, 4096) int32

  int* out = (int*)d_out;  // [tags: 128*4096][lens: 128]
  int* tags_out = out;
  int* lens_out = out + (size_t)BATCH * TLEN;

  // workspace layout
  char* w = (char*)d_ws;
  unsigned char* bp = (unsigned char*)w;                     // 33,554,432 B
  float* cp = (float*)(bp + (size_t)BATCH * TLEN * KS);      //  2,097,152 B
  float* fin = cp + (size_t)BATCH * NCHUNK * KS;             //     32,768 B
  unsigned char* map = (unsigned char*)(fin + (size_t)BATCH * KS);  // 524,288 B
  unsigned char* e = map + (size_t)BATCH * NCHUNK * KS;      //      8,192 B

  crf_fwd<<<BATCH / 2, 64, 0, stream>>>(pot, trans, cp, fin);
  crf_lens<<<BATCH, 64, 0, stream>>>(mask, lens_out);
  crf_bp<<<dim3(BATCH, NCHUNK), 64, 0, stream>>>(pot, trans, cp, bp, map);
  crf_compose<<<1, BATCH, 0, stream>>>(map, fin, e, tags_out);
  crf_extract<<<(BATCH * NCHUNK + 255) / 256, 256, 0, stream>>>(bp, e, tags_out);
}

// Round 5
// 2004.732 us; speedup vs baseline: 1.8898x; 1.8898x over previous
//
#include <hip/hip_runtime.h>
#include <cstdint>
#include <cstddef>

#define BATCH 128
#define TLEN 4096
#define KS 64
#define NCHUNK 64  // chunk c covers t in [64c+1, min(64c+64, 4095)]

__device__ __forceinline__ float f3(float a, float b, float c) {
  return fmaxf(fmaxf(a, b), c);  // folds to v_max3_f32
}

// max over m[64] without clobbering m. 31 max3 + 1 fmax, depth 5.
// fp32 max returns an input bitwise, so any tree shape gives states
// bit-identical to the reference's pairwise max.
__device__ __forceinline__ float tree64(const float* m) {
  float t[22];
#pragma unroll
  for (int i = 0; i < 21; ++i) t[i] = f3(m[3 * i], m[3 * i + 1], m[3 * i + 2]);
  t[21] = m[63];
#pragma unroll
  for (int i = 0; i < 7; ++i) t[i] = f3(t[3 * i], t[3 * i + 1], t[3 * i + 2]);
  t[7] = t[21];
  t[0] = f3(t[0], t[1], t[2]);
  t[1] = f3(t[3], t[4], t[5]);
  t[2] = t[6];
  t[3] = t[7];
  t[0] = f3(t[0], t[1], t[2]);
  return fmaxf(t[0], t[3]);
}

// ---------------------------------------------------------------------------
// Forward recurrence (round-3 structure + VGPR-pinned transition column).
// One wave per batch; LDS broadcast with no barrier (single-wave in-order
// LDS). The asm pin makes rematerializing the trans loads inside the t-loop
// illegal, forcing the 64-entry column to stay resident in VGPRs — round 3/4
// counters (VGPR_Count 72/136) proved the compiler otherwise reloads it from
// L1 on the serial critical path every step.
// ---------------------------------------------------------------------------
__global__ __launch_bounds__(64, 1) void crf_fwd(
    const float* __restrict__ pot, const float* __restrict__ trans,
    float* __restrict__ cp, float* __restrict__ fin) {
  const int b = blockIdx.x;
  const int j = threadIdx.x;
  __shared__ float4 sm4[KS / 4];
  float* sm = (float*)sm4;

  float c[KS];
#pragma unroll
  for (int i = 0; i < KS; ++i) c[i] = trans[i * KS + j];
#pragma unroll
  for (int i = 0; i < KS; ++i) asm volatile("" : "+v"(c[i]));  // pin in VGPRs

  const float* pb = pot + (size_t)b * TLEN * KS + j;
  float* cpb = cp + (size_t)b * NCHUNK * KS + j;

  float s = pb[0];
  cpb[0] = s;
  sm[j] = s;

  // 4-deep emission prefetch ring (HBM latency ~900 cyc ≈ 3 steps)
  float ef[4];
#pragma unroll
  for (int q = 0; q < 4; ++q) ef[q] = pb[(size_t)(1 + q) * KS];

#pragma unroll 4
  for (int t = 1; t < TLEN; ++t) {
    float emit = ef[(t - 1) & 3];
    int tp = t + 4;
    tp = tp > TLEN - 1 ? TLEN - 1 : tp;
    ef[(t - 1) & 3] = pb[(size_t)tp * KS];

    // broadcast-read full state vector (same-address b128 reads: no conflicts)
    float m[KS];
#pragma unroll
    for (int q = 0; q < KS / 4; ++q) {
      float4 v = sm4[q];
      m[4 * q + 0] = v.x + c[4 * q + 0];
      m[4 * q + 1] = v.y + c[4 * q + 1];
      m[4 * q + 2] = v.z + c[4 * q + 2];
      m[4 * q + 3] = v.w + c[4 * q + 3];
    }
    s = tree64(m) + emit;
    sm[j] = s;  // single-wave in-order LDS: next iteration's reads see this
    if ((t & 63) == 0) cpb[(size_t)(t >> 6) * KS] = s;
  }
  fin[(size_t)b * KS + j] = s;
}

// ---------------------------------------------------------------------------
// Backpointer reconstruction: per (batch, chunk) wave recomputes states from
// the checkpoint (bit-identical: fp32 max is exact, sums identical), derives
// bp[t][j] for all j, and fuses the speculative chunk-map chase via
// ds_bpermute. 8192 waves -> latency hidden by TLP; NOT pinned (pinning 64
// VGPRs here would crash its 8-waves/SIMD occupancy).
// ---------------------------------------------------------------------------
__global__ __launch_bounds__(64) void crf_bp(
    const float* __restrict__ pot, const float* __restrict__ trans,
    const float* __restrict__ cp, unsigned char* __restrict__ bp,
    unsigned char* __restrict__ map) {
  const int b = blockIdx.x;
  const int ch = blockIdx.y;
  const int j = threadIdx.x;
  __shared__ float4 sm4[KS / 4];
  float* sm = (float*)sm4;

  float c[KS];
#pragma unroll
  for (int i = 0; i < KS; ++i) c[i] = trans[i * KS + j];

  float s = cp[((size_t)b * NCHUNK + ch) * KS + j];
  const int t0 = ch * 64;
  const int hi = min(t0 + 64, TLEN - 1);
  const float* pb = pot + (size_t)b * TLEN * KS + j;
  unsigned char* bpb = bp + (size_t)b * TLEN * KS + j;

  sm[j] = s;
  int tag = j;  // forward-composed backward map
  float emit = pb[(size_t)(t0 + 1) * KS];
  for (int t = t0 + 1; t <= hi; ++t) {
    float emit_next = pb[(size_t)min(t + 1, TLEN - 1) * KS];

    float m[KS];
#pragma unroll
    for (int q = 0; q < KS / 4; ++q) {
      float4 v = sm4[q];
      m[4 * q + 0] = v.x + c[4 * q + 0];
      m[4 * q + 1] = v.y + c[4 * q + 1];
      m[4 * q + 2] = v.z + c[4 * q + 2];
      m[4 * q + 3] = v.w + c[4 * q + 3];
    }
    float best = tree64(m);

    // first-occurrence argmax: descending exact-equality scan
    int bi = 63;
#pragma unroll
    for (int i = 62; i >= 0; --i) bi = (m[i] == best) ? i : bi;

    bpb[(size_t)t * KS] = (unsigned char)bi;
    s = best + emit;
    sm[j] = s;
    emit = emit_next;

    // g_t[k] = g_{t-1}[bp_t[k]]: lane k pulls lane bi_k's tag
    tag = __builtin_amdgcn_ds_bpermute(bi << 2, tag);
  }
  map[((size_t)b * NCHUNK + ch) * KS + j] = (unsigned char)tag;
}

// ---------------------------------------------------------------------------
// Compose chunk maps per batch (serial over 64 chunks, parallel over batches).
// Also does the final-state argmax (first-occurrence, strict >).
// ---------------------------------------------------------------------------
__global__ void crf_compose(const unsigned char* __restrict__ map,
                            const float* __restrict__ fin,
                            unsigned char* __restrict__ e,
                            int* __restrict__ tags_out) {
  const int b = blockIdx.x * blockDim.x + threadIdx.x;
  if (b >= BATCH) return;
  const float* fb = fin + (size_t)b * KS;
  float best = fb[0];
  int cur = 0;
  for (int i = 1; i < KS; ++i) {
    float v = fb[i];
    if (v > best) { best = v; cur = i; }
  }
  tags_out[(size_t)b * TLEN + (TLEN - 1)] = cur;
  for (int ch = NCHUNK - 1; ch >= 0; --ch) {
    e[(size_t)b * NCHUNK + ch] = (unsigned char)cur;
    cur = map[((size_t)b * NCHUNK + ch) * KS + cur];
  }
}

// ---------------------------------------------------------------------------
// Extract per-chunk paths from known entering tags (parallel over B*NCHUNK).
// ---------------------------------------------------------------------------
__global__ void crf_extract(const unsigned char* __restrict__ bp,
                            const unsigned char* __restrict__ e,
                            int* __restrict__ tags_out) {
  const int idx = blockIdx.x * blockDim.x + threadIdx.x;  // b*NCHUNK + c
  if (idx >= BATCH * NCHUNK) return;
  const int b = idx >> 6;
  const int c = idx & (NCHUNK - 1);
  const int lo = 64 * c + 1;
  const int hi = min(64 * c + 64, TLEN - 1);
  const unsigned char* bpb = bp + (size_t)b * TLEN * KS;
  int* to = tags_out + (size_t)b * TLEN;
  int tag = e[(size_t)b * NCHUNK + c];
  for (int t = hi; t >= lo; --t) {
    tag = bpb[(size_t)t * KS + tag];
    to[t - 1] = tag;
  }
}

// ---------------------------------------------------------------------------
// Sequence lengths = sum(mask) per batch.
// ---------------------------------------------------------------------------
__global__ __launch_bounds__(64) void crf_lens(const int* __restrict__ mask,
                                               int* __restrict__ out) {
  const int b = blockIdx.x;
  const int l = threadIdx.x;
  const int* mb = mask + (size_t)b * TLEN;
  int sum = 0;
  for (int t = l; t < TLEN; t += 64) sum += mb[t];
#pragma unroll
  for (int off = 32; off > 0; off >>= 1) sum += __shfl_down(sum, off, 64);
  if (l == 0) out[b] = sum;
}

extern "C" void kernel_launch(void* const* d_in, const int* in_sizes, int n_in,
                              void* d_out, int out_size, void* d_ws,
                              size_t ws_size, hipStream_t stream) {
  const float* pot = (const float*)d_in[0];    // (128, 4096, 64) fp32
  const float* trans = (const float*)d_in[1];  // (64, 64) fp32
  const int* mask = (const int*)d_in[2];       // (128, 4096) int32

  int* out = (int*)d_out;  // [tags: 128*4096][lens: 128]
  int* tags_out = out;
  int* lens_out = out + (size_t)BATCH * TLEN;

  // workspace layout
  char* w = (char*)d_ws;
  unsigned char* bp = (unsigned char*)w;                     // 33,554,432 B
  float* cp = (float*)(bp + (size_t)BATCH * TLEN * KS);      //  2,097,152 B
  float* fin = cp + (size_t)BATCH * NCHUNK * KS;             //     32,768 B
  unsigned char* map = (unsigned char*)(fin + (size_t)BATCH * KS);  // 524,288 B
  unsigned char* e = map + (size_t)BATCH * NCHUNK * KS;      //      8,192 B

  crf_fwd<<<BATCH, 64, 0, stream>>>(pot, trans, cp, fin);
  crf_lens<<<BATCH, 64, 0, stream>>>(mask, lens_out);
  crf_bp<<<dim3(BATCH, NCHUNK), 64, 0, stream>>>(pot, trans, cp, bp, map);
  crf_compose<<<1, BATCH, 0, stream>>>(map, fin, e, tags_out);
  crf_extract<<<(BATCH * NCHUNK + 255) / 256, 256, 0, stream>>>(bp, e, tags_out);
}